// Round 1
// baseline (40331.140 us; speedup 1.0000x reference)
//
#include <hip/hip_runtime.h>
#include <stdint.h>

#define B_ 64
#define S_ 512
#define I_ 1024
#define H_ 1024

typedef _Float16 f16;
typedef _Float16 f16x8 __attribute__((ext_vector_type(8)));
typedef float f32x4 __attribute__((ext_vector_type(4)));

__device__ __forceinline__ f32x4 mfma16(f16x8 a, f16x8 b, f32x4 c) {
    return __builtin_amdgcn_mfma_f32_16x16x32_f16(a, b, c, 0, 0, 0);
}
__device__ __forceinline__ float sigm(float x)  { return 1.f / (1.f + __expf(-x)); }
__device__ __forceinline__ float tanh_(float x) { return 1.f - 2.f / (1.f + __expf(2.f * x)); }

__device__ __forceinline__ f16x8 cvt8(const float* p) {
    float4 u = *reinterpret_cast<const float4*>(p);
    float4 v = *reinterpret_cast<const float4*>(p + 4);
    return f16x8{(f16)u.x,(f16)u.y,(f16)u.z,(f16)u.w,
                 (f16)v.x,(f16)v.y,(f16)v.z,(f16)v.w};
}

// ---------------------------------------------------------------------------
// tf_mask dtype detector (unchanged from baseline): 1 => 4-byte elems.
// ---------------------------------------------------------------------------
__global__ void detect_mask(const unsigned int* __restrict__ m, int* __restrict__ flag) {
    __shared__ int ok;
    if (threadIdx.x == 0) ok = 1;
    __syncthreads();
    unsigned w = m[threadIdx.x];                    // 128 threads -> 512 bytes
    bool is4 = (w == 0u) || (w == 1u) || (w == 0x3F800000u);
    if (!is4) atomicAnd(&ok, 0);
    __syncthreads();
    if (threadIdx.x == 0) *flag = ok;
}

// ---------------------------------------------------------------------------
// Two-level monotonic grid barrier (device scope). 256 blocks, 32 leaves of 8.
// Counters only ever increase -> no reset, no ABA. Re-zeroed per graph replay
// by a captured hipMemsetAsync. Release/acquire = __threadfence() (agent-scope
// wbL2 / inv) around the LLC-serialized arrival atomics.
// ---------------------------------------------------------------------------
__device__ __forceinline__ void gbar(int* root, int* leaf, int bar, int blk) {
    __syncthreads();                               // all block stores complete (vmcnt drain)
    if (threadIdx.x == 0) {
        __threadfence();                           // release: my XCD L2 -> LLC
        const int lf = blk & 31;                   // leaf counters 128 B apart
        const int old = atomicAdd(leaf + lf * 32, 1);
        if (old == bar * 8 - 1) atomicAdd(root, 1);   // last of 8 in this round
        const int tgt = bar * 32;
        while (__hip_atomic_load(root, __ATOMIC_RELAXED, __HIP_MEMORY_SCOPE_AGENT) < tgt)
            __builtin_amdgcn_s_sleep(1);
        __threadfence();                           // acquire: inv L1/L2 before h reads
    }
    __syncthreads();
}

// ---------------------------------------------------------------------------
// One LSTM step, persistent version. Block owns h-cols [4*blk, 4*blk+4) for
// all 4 gates (16 gate-cols = one MFMA N-tile; lane col r -> gate r>>2,
// h-col 4*blk + (r&3)). Waves split K=2048 stride-4 (wave w takes K-steps
// kk = 4i+w); weight frags live in registers (wf[16] = 64 VGPR). Partial
// gate sums reduced across the 4 waves through LDS, then the cell update
// runs one thread per (row, h-col) with c held in a register.
// ---------------------------------------------------------------------------
template<bool XF32>
__device__ __forceinline__ void cell_step(
    const void* xsrc, long xstr,
    const f16x8 (&wf)[16],
    const f16* hin, f16* hout,
    float& c, const float (&bias)[4],
    float (&part)[4][64][17],
    int blk, int w, int r, int q, int tid)
{
    const f32x4 z = {0.f, 0.f, 0.f, 0.f};
    f32x4 acc[4] = {z, z, z, z};
    #pragma unroll
    for (int i = 0; i < 8; ++i) {                  // x/inp half of K
        const int kk = 4 * i + w;
        #pragma unroll
        for (int m = 0; m < 4; ++m) {
            const long off = (long)(16 * m + r) * xstr + kk * 32 + q * 8;
            f16x8 a;
            if constexpr (XF32) a = cvt8((const float*)xsrc + off);
            else                a = *reinterpret_cast<const f16x8*>((const f16*)xsrc + off);
            acc[m] = mfma16(a, wf[i], acc[m]);
        }
    }
    #pragma unroll
    for (int i = 8; i < 16; ++i) {                 // h half of K
        const int kh = 4 * (i - 8) + w;
        #pragma unroll
        for (int m = 0; m < 4; ++m) {
            const f16* p = hin + (long)(16 * m + r) * H_ + kh * 32 + q * 8;
            acc[m] = mfma16(*reinterpret_cast<const f16x8*>(p), wf[i], acc[m]);
        }
    }
    // C/D layout: col = r, row-in-tile = q*4 + t2 (proven in baseline kernel)
    #pragma unroll
    for (int m = 0; m < 4; ++m)
        #pragma unroll
        for (int t2 = 0; t2 < 4; ++t2)
            part[w][16 * m + q * 4 + t2][r] = acc[m][t2];
    __syncthreads();
    const int row = tid >> 2, jj = tid & 3;        // one cell per thread
    float gv[4];
    #pragma unroll
    for (int g2 = 0; g2 < 4; ++g2)
        gv[g2] = part[0][row][g2 * 4 + jj] + part[1][row][g2 * 4 + jj]
               + part[2][row][g2 * 4 + jj] + part[3][row][g2 * 4 + jj] + bias[g2];
    const float iv = sigm(gv[0]), fv = sigm(gv[1]);
    const float gg = tanh_(gv[2]), ov = sigm(gv[3]);
    c = fv * c + iv * gg;
    hout[(long)row * H_ + 4 * blk + jj] = (f16)(ov * tanh_(c));
}

// ---------------------------------------------------------------------------
// Persistent whole-sequence kernel. 256 blocks x 256 threads, all co-resident
// (<=256 VGPR via launch_bounds(256,2), 51 KB LDS -> capacity >= 2 blocks/CU,
// so the grid barrier cannot deadlock). Weights are gathered ONCE into
// registers/LDS; 1536 kernel launches become 1536 ~1us barriers.
// ---------------------------------------------------------------------------
__global__ __launch_bounds__(256, 2) void seq2seq(
    const float* __restrict__ x, const float* __restrict__ target,
    const float* __restrict__ eWih, const float* __restrict__ eWhh, const float* __restrict__ eb,
    const float* __restrict__ dWih, const float* __restrict__ dWhh, const float* __restrict__ db,
    const float* __restrict__ fcW, const float* __restrict__ fcb,
    const unsigned char* __restrict__ mask, const int* __restrict__ flag,
    f16* hA, f16* hB, f16* nxt, float* __restrict__ out,
    int* root, int* leaf)
{
    const int blk = blockIdx.x, tid = threadIdx.x;
    const int w = tid >> 6, lane = tid & 63;
    const int r = lane & 15, q = lane >> 4;

    __shared__ float part[4][64][17];              // +1 pad: kills 4-way LDS conflicts
    __shared__ f16 wFs[16][1040];                  // fc slice (blk<64); 1040 = 1024+16 pad

    // ---- one-time weight gather: f32 global -> f16 register frags ----
    f16x8 wE[16], wD[16];
    {
        const long Wrow = (long)(r >> 2) * H_ + 4 * blk + (r & 3);
        #pragma unroll
        for (int i = 0; i < 16; ++i) {
            const int kk = 4 * i + w;
            const long off = (kk < 32) ? (Wrow * I_ + kk * 32 + q * 8)
                                       : (Wrow * H_ + (kk - 32) * 32 + q * 8);
            wE[i] = cvt8(((kk < 32) ? eWih : eWhh) + off);
            wD[i] = cvt8(((kk < 32) ? dWih : dWhh) + off);
        }
    }
    if (blk < 64) {                                // fc weights -> LDS (saves 32 VGPR)
        for (int idx = tid; idx < 16 * 1024; idx += 256) {
            const int r2 = idx >> 10, k = idx & 1023;
            wFs[r2][k] = (f16)fcW[(long)(16 * blk + r2) * H_ + k];
        }
    }
    float bE[4], bD[4];
    #pragma unroll
    for (int g2 = 0; g2 < 4; ++g2) {
        bE[g2] = eb[g2 * H_ + 4 * blk + (tid & 3)];
        bD[g2] = db[g2 * H_ + 4 * blk + (tid & 3)];
    }
    const float bF = (blk < 64) ? fcb[16 * blk + (tid & 15)] : 0.f;
    const int f4 = *flag;

    // decoder step-0 input: x[:, S-1, :] -> f16 into nxt (65536 threads, 1 elem each;
    // 512 encoder barriers separate this write from its first read)
    {
        const int gt = blk * 256 + tid;
        const int row = gt >> 10, col = gt & 1023;
        nxt[(long)row * I_ + col] = (f16)x[(long)row * (S_ * I_) + (long)(S_ - 1) * I_ + col];
    }

    float c = 0.f;                                 // cell state lives in a register
    int bar = 0;
    f16* hin = hA; f16* hout = hB;                 // ping-pong: 1 barrier/step suffices

    // ---- encoder: 512 steps ----
    for (int s = 0; s < S_; ++s) {
        cell_step<true>(x + (long)s * I_, (long)(S_ * I_), wE, hin, hout, c, bE, part,
                        blk, w, r, q, tid);
        gbar(root, leaf, ++bar, blk);
        f16* t_ = hin; hin = hout; hout = t_;
    }

    // ---- decoder: 512 steps (cell -> bar -> pred -> bar) ----
    for (int t = 0; t < S_; ++t) {
        cell_step<false>(nxt, (long)I_, wD, hin, hout, c, bD, part, blk, w, r, q, tid);
        gbar(root, leaf, ++bar, blk);
        if (blk < 64) {                            // pred = h @ fcW^T + fcb; blocks 64..255 idle-spin
            const f32x4 z = {0.f, 0.f, 0.f, 0.f};
            f32x4 pa[4] = {z, z, z, z};
            #pragma unroll
            for (int i = 0; i < 8; ++i) {
                const int kk = 4 * i + w;
                const f16x8 bf = *reinterpret_cast<const f16x8*>(&wFs[r][kk * 32 + q * 8]);
                #pragma unroll
                for (int m = 0; m < 4; ++m) {
                    const f16* p = hout + (long)(16 * m + r) * H_ + kk * 32 + q * 8;
                    pa[m] = mfma16(*reinterpret_cast<const f16x8*>(p), bf, pa[m]);
                }
            }
            #pragma unroll
            for (int m = 0; m < 4; ++m)
                #pragma unroll
                for (int t2 = 0; t2 < 4; ++t2)
                    part[w][16 * m + q * 4 + t2][r] = pa[m][t2];
            __syncthreads();
            const bool msk = f4 ? (reinterpret_cast<const int*>(mask)[t] != 0)
                                : (mask[t] != 0);
            const int cl = tid & 15, rb = (tid >> 4) << 2;
            const int colg = 16 * blk + cl;
            #pragma unroll
            for (int e = 0; e < 4; ++e) {
                const int row = rb + e;
                const float pv = part[0][row][cl] + part[1][row][cl]
                               + part[2][row][cl] + part[3][row][cl] + bF;
                const long oidx = (long)row * (S_ * I_) + (long)t * I_ + colg;
                out[oidx] = pv;
                const float nv = msk ? target[oidx] : pv;
                nxt[(long)row * I_ + colg] = (f16)nv;
            }
        }
        gbar(root, leaf, ++bar, blk);
        f16* t_ = hin; hin = hout; hout = t_;
    }
}

// ---------------------------------------------------------------------------
extern "C" void kernel_launch(void* const* d_in, const int* in_sizes, int n_in,
                              void* d_out, int out_size, void* d_ws, size_t ws_size,
                              hipStream_t stream) {
    (void)in_sizes; (void)n_in; (void)out_size; (void)ws_size;
    const float* x       = (const float*)d_in[0];
    const float* target  = (const float*)d_in[1];
    const float* enc_Wih = (const float*)d_in[2];
    const float* enc_Whh = (const float*)d_in[3];
    const float* enc_b   = (const float*)d_in[4];
    const float* dec_Wih = (const float*)d_in[5];
    const float* dec_Whh = (const float*)d_in[6];
    const float* dec_b   = (const float*)d_in[7];
    const float* fc_W    = (const float*)d_in[8];
    const float* fc_b    = (const float*)d_in[9];
    const void*  tfmask  = d_in[10];

    uint8_t* p = (uint8_t*)d_ws;
    auto carve = [&](size_t bytes) { void* rv = (void*)p; p += (bytes + 255) & ~(size_t)255; return rv; };
    f16* hA   = (f16*)carve((size_t)B_ * H_ * 2);
    f16* hB   = (f16*)carve((size_t)B_ * H_ * 2);
    f16* nxt  = (f16*)carve((size_t)B_ * I_ * 2);
    int* flag = (int*)carve(256);
    int* bars = (int*)carve(8192);    // bars[0]=root, bars[32 + lf*32]=leaf lf

    detect_mask<<<1, 128, 0, stream>>>((const unsigned int*)tfmask, flag);
    hipMemsetAsync(hA, 0, (size_t)B_ * H_ * 2, stream);      // h0 = 0 (replay-safe)
    hipMemsetAsync(bars, 0, 8192, stream);                   // barrier counters = 0 per replay

    seq2seq<<<256, 256, 0, stream>>>(
        x, target, enc_Wih, enc_Whh, enc_b, dec_Wih, dec_Whh, dec_b, fc_W, fc_b,
        (const unsigned char*)tfmask, flag, hA, hB, nxt, (float*)d_out,
        bars, bars + 32);
}

// Round 2
// 32853.763 us; speedup vs baseline: 1.2276x; 1.2276x over previous
//
#include <hip/hip_runtime.h>
#include <stdint.h>

#define B_ 64
#define S_ 512
#define I_ 1024
#define H_ 1024

typedef _Float16 f16;
typedef _Float16 f16x8 __attribute__((ext_vector_type(8)));
typedef float f32x4 __attribute__((ext_vector_type(4)));

__device__ __forceinline__ f32x4 mfma16(f16x8 a, f16x8 b, f32x4 c) {
    return __builtin_amdgcn_mfma_f32_16x16x32_f16(a, b, c, 0, 0, 0);
}
__device__ __forceinline__ float sigm(float x)  { return 1.f / (1.f + __expf(-x)); }
__device__ __forceinline__ float tanh_(float x) { return 1.f - 2.f / (1.f + __expf(2.f * x)); }

__device__ __forceinline__ f16x8 cvt8(const float* p) {
    float4 u = *reinterpret_cast<const float4*>(p);
    float4 v = *reinterpret_cast<const float4*>(p + 4);
    return f16x8{(f16)u.x,(f16)u.y,(f16)u.z,(f16)u.w,
                 (f16)v.x,(f16)v.y,(f16)v.z,(f16)v.w};
}

// ---- LLC-coherent (sc0 sc1) access helpers: no stale L1/L2 possible, so the
// ---- grid barrier needs NO cache-maintenance (no buffer_wbl2 / buffer_inv).
__device__ __forceinline__ f16x8 ld16cg(const f16* p) {   // 16B as 2x 8B agent loads
    union { unsigned long long u[2]; f16x8 v; } t;
    t.u[0] = __hip_atomic_load((const unsigned long long*)p,
                               __ATOMIC_RELAXED, __HIP_MEMORY_SCOPE_AGENT);
    t.u[1] = __hip_atomic_load((const unsigned long long*)(p + 4),
                               __ATOMIC_RELAXED, __HIP_MEMORY_SCOPE_AGENT);
    return t.v;
}
__device__ __forceinline__ void st8cg(f16* p, float a, float b, float c, float d) {
    union { f16 h[4]; unsigned long long u; } t;
    t.h[0] = (f16)a; t.h[1] = (f16)b; t.h[2] = (f16)c; t.h[3] = (f16)d;
    __hip_atomic_store((unsigned long long*)p, t.u,
                       __ATOMIC_RELAXED, __HIP_MEMORY_SCOPE_AGENT);
}

// ---------------------------------------------------------------------------
// tf_mask dtype detector (unchanged): 1 => 4-byte elems.
// ---------------------------------------------------------------------------
__global__ void detect_mask(const unsigned int* __restrict__ m, int* __restrict__ flag) {
    __shared__ int ok;
    if (threadIdx.x == 0) ok = 1;
    __syncthreads();
    unsigned w = m[threadIdx.x];
    bool is4 = (w == 0u) || (w == 1u) || (w == 0x3F800000u);
    if (!is4) atomicAnd(&ok, 0);
    __syncthreads();
    if (threadIdx.x == 0) *flag = ok;
}

// ---------------------------------------------------------------------------
// Fence-free two-level monotonic grid barrier. All shared stores are sc1
// write-through (at LLC once vmcnt drains, which __syncthreads guarantees);
// all shared loads bypass L1/L2 -> no invalidate needed. Counters only grow.
// ---------------------------------------------------------------------------
__device__ __forceinline__ void gbar(int* root, int* leaf, int bar, int blk) {
    asm volatile("s_waitcnt vmcnt(0)" ::: "memory");   // my sc1 stores at LLC
    __syncthreads();                                   // all waves drained
    if (threadIdx.x == 0) {
        const int lf  = blk & 31;
        const int old = __hip_atomic_fetch_add(leaf + lf * 32, 1,
                            __ATOMIC_RELAXED, __HIP_MEMORY_SCOPE_AGENT);
        if (old == bar * 8 - 1)
            __hip_atomic_fetch_add(root, 1, __ATOMIC_RELAXED, __HIP_MEMORY_SCOPE_AGENT);
        const int tgt = bar * 32;
        while (__hip_atomic_load(root, __ATOMIC_RELAXED, __HIP_MEMORY_SCOPE_AGENT) < tgt)
            __builtin_amdgcn_s_sleep(1);
    }
    __syncthreads();
}

// ---------------------------------------------------------------------------
// One LSTM step. Block owns h-cols [4*blk,4*blk+4) (16 gate-cols = one MFMA
// N-tile; lane col r -> gate r>>2, h-col r&3). Waves split K=2048 stride-4;
// weights live in registers. Wave partials reduced through LDS; cell update:
// thread row (tid<64) owns 4 h-cols, c[4] in registers, one 8B sc1 store.
// ---------------------------------------------------------------------------
template<bool XF32>
__device__ __forceinline__ void cell_step(
    const void* xsrc, long xstr,
    const f16x8 (&wf)[16],
    const f16* hin, f16* hout,
    float (&c)[4], const f32x4 (&bias)[4],
    float (&part)[4][64][17],
    int blk, int w, int r, int q, int tid)
{
    const f32x4 z = {0.f, 0.f, 0.f, 0.f};
    f32x4 acc[4] = {z, z, z, z};
    #pragma unroll
    for (int i = 0; i < 8; ++i) {                  // x/inp half of K
        const int kk = 4 * i + w;
        #pragma unroll
        for (int m = 0; m < 4; ++m) {
            const long off = (long)(16 * m + r) * xstr + kk * 32 + q * 8;
            f16x8 a;
            if constexpr (XF32) a = cvt8((const float*)xsrc + off);   // immutable x: cached
            else                a = ld16cg((const f16*)xsrc + off);   // nxt: LLC-coherent
            acc[m] = mfma16(a, wf[i], acc[m]);
        }
    }
    #pragma unroll
    for (int i = 8; i < 16; ++i) {                 // h half of K (LLC-coherent)
        const int kh = 4 * (i - 8) + w;
        #pragma unroll
        for (int m = 0; m < 4; ++m)
            acc[m] = mfma16(ld16cg(hin + (long)(16 * m + r) * H_ + kh * 32 + q * 8),
                            wf[i], acc[m]);
    }
    #pragma unroll
    for (int m = 0; m < 4; ++m)
        #pragma unroll
        for (int t2 = 0; t2 < 4; ++t2)
            part[w][16 * m + q * 4 + t2][r] = acc[m][t2];
    __syncthreads();
    if (tid < 64) {                                // row = tid, 4 h-cols
        const int row = tid;
        float hv[4];
        #pragma unroll
        for (int jj = 0; jj < 4; ++jj) {
            float gv[4];
            #pragma unroll
            for (int g = 0; g < 4; ++g)
                gv[g] = part[0][row][g * 4 + jj] + part[1][row][g * 4 + jj]
                      + part[2][row][g * 4 + jj] + part[3][row][g * 4 + jj] + bias[g][jj];
            const float iv = sigm(gv[0]), fv = sigm(gv[1]);
            const float gg = tanh_(gv[2]), ov = sigm(gv[3]);
            c[jj] = fv * c[jj] + iv * gg;
            hv[jj] = ov * tanh_(c[jj]);
        }
        st8cg(hout + (long)row * H_ + 4 * blk, hv[0], hv[1], hv[2], hv[3]);
    }
}

// ---------------------------------------------------------------------------
// Persistent whole-sequence kernel. 256 blocks x 256 threads, co-resident
// (launch_bounds(256,2), 50.7 KB LDS -> capacity >= 2 blocks/CU).
// ---------------------------------------------------------------------------
__global__ __launch_bounds__(256, 2) void seq2seq(
    const float* __restrict__ x, const float* __restrict__ target,
    const float* __restrict__ eWih, const float* __restrict__ eWhh, const float* __restrict__ eb,
    const float* __restrict__ dWih, const float* __restrict__ dWhh, const float* __restrict__ db,
    const float* __restrict__ fcW, const float* __restrict__ fcb,
    const unsigned char* __restrict__ mask, const int* __restrict__ flag,
    f16* hA, f16* hB, f16* nxt, float* __restrict__ out,
    int* root, int* leaf)
{
    const int blk = blockIdx.x, tid = threadIdx.x;
    const int w = tid >> 6, lane = tid & 63;
    const int r = lane & 15, q = lane >> 4;

    __shared__ float part[4][64][17];              // +1 pad
    __shared__ f16 wFs[16][1040];                  // fc slice (blk<64)

    // ---- one-time weight gather: f32 global -> f16 register frags ----
    f16x8 wE[16], wD[16];
    {
        const long Wrow = (long)(r >> 2) * H_ + 4 * blk + (r & 3);
        #pragma unroll
        for (int i = 0; i < 16; ++i) {
            const int kk = 4 * i + w;
            const long off = (kk < 32) ? (Wrow * I_ + kk * 32 + q * 8)
                                       : (Wrow * H_ + (kk - 32) * 32 + q * 8);
            wE[i] = cvt8(((kk < 32) ? eWih : eWhh) + off);
            wD[i] = cvt8(((kk < 32) ? dWih : dWhh) + off);
        }
    }
    if (blk < 64) {
        for (int idx = tid; idx < 16 * 1024; idx += 256) {
            const int r2 = idx >> 10, k = idx & 1023;
            wFs[r2][k] = (f16)fcW[(long)(16 * blk + r2) * H_ + k];
        }
    }
    f32x4 bE[4], bD[4];
    #pragma unroll
    for (int g = 0; g < 4; ++g) {
        bE[g] = *reinterpret_cast<const f32x4*>(eb + g * H_ + 4 * blk);
        bD[g] = *reinterpret_cast<const f32x4*>(db + g * H_ + 4 * blk);
    }
    const int f4 = *flag;

    // decoder step-0 input: x[:, S-1, :] -> f16 into nxt (sc1 stores: readers
    // bypass L2, so the init must reach the LLC; 512 barriers separate it).
    {
        const int gt = blk * 256 + tid;            // 65536 threads
        if (gt < 16384) {                          // 4 elems each
            const int row = gt >> 8, cg = (gt & 255) * 4;
            float4 v = *reinterpret_cast<const float4*>(
                x + (long)row * (S_ * I_) + (long)(S_ - 1) * I_ + cg);
            st8cg(nxt + (long)row * I_ + cg, v.x, v.y, v.z, v.w);
        }
    }

    float c[4] = {0.f, 0.f, 0.f, 0.f};
    int bar = 0;
    f16* hin = hA; f16* hout = hB;

    // ---- encoder: 512 steps ----
    for (int s = 0; s < S_; ++s) {
        cell_step<true>(x + (long)s * I_, (long)(S_ * I_), wE, hin, hout, c, bE, part,
                        blk, w, r, q, tid);
        gbar(root, leaf, ++bar, blk);
        f16* t_ = hin; hin = hout; hout = t_;
    }

    // ---- decoder: 512 steps (cell -> bar -> pred -> bar) ----
    for (int t = 0; t < S_; ++t) {
        cell_step<false>(nxt, (long)I_, wD, hin, hout, c, bD, part, blk, w, r, q, tid);
        gbar(root, leaf, ++bar, blk);
        if (blk < 64) {                            // pred = h @ fcW^T + fcb
            const f32x4 z = {0.f, 0.f, 0.f, 0.f};
            f32x4 pa[4] = {z, z, z, z};
            #pragma unroll
            for (int i = 0; i < 8; ++i) {
                const int kk = 4 * i + w;
                const f16x8 bf = *reinterpret_cast<const f16x8*>(&wFs[r][kk * 32 + q * 8]);
                #pragma unroll
                for (int m = 0; m < 4; ++m)
                    pa[m] = mfma16(ld16cg(hout + (long)(16 * m + r) * H_ + kk * 32 + q * 8),
                                   bf, pa[m]);
            }
            #pragma unroll
            for (int m = 0; m < 4; ++m)
                #pragma unroll
                for (int t2 = 0; t2 < 4; ++t2)
                    part[w][16 * m + q * 4 + t2][r] = pa[m][t2];
            __syncthreads();
            const bool msk = f4 ? (reinterpret_cast<const int*>(mask)[t] != 0)
                                : (mask[t] != 0);
            const int prow = tid >> 2;             // 0..63
            const int pcg  = (tid & 3) * 4;        // col group within 16
            const f32x4 bF = *reinterpret_cast<const f32x4*>(fcb + 16 * blk + pcg);
            float pv[4];
            #pragma unroll
            for (int e = 0; e < 4; ++e)
                pv[e] = part[0][prow][pcg + e] + part[1][prow][pcg + e]
                      + part[2][prow][pcg + e] + part[3][prow][pcg + e] + bF[e];
            const long obase = (long)prow * (S_ * I_) + (long)t * I_ + 16 * blk + pcg;
            *reinterpret_cast<f32x4*>(out + obase) = {pv[0], pv[1], pv[2], pv[3]};
            float nv[4];
            if (msk) {
                const f32x4 tg = *reinterpret_cast<const f32x4*>(target + obase);
                nv[0] = tg[0]; nv[1] = tg[1]; nv[2] = tg[2]; nv[3] = tg[3];
            } else {
                nv[0] = pv[0]; nv[1] = pv[1]; nv[2] = pv[2]; nv[3] = pv[3];
            }
            st8cg(nxt + (long)prow * I_ + 16 * blk + pcg, nv[0], nv[1], nv[2], nv[3]);
        }
        gbar(root, leaf, ++bar, blk);
        f16* t_ = hin; hin = hout; hout = t_;
    }
}

// ---------------------------------------------------------------------------
extern "C" void kernel_launch(void* const* d_in, const int* in_sizes, int n_in,
                              void* d_out, int out_size, void* d_ws, size_t ws_size,
                              hipStream_t stream) {
    (void)in_sizes; (void)n_in; (void)out_size; (void)ws_size;
    const float* x       = (const float*)d_in[0];
    const float* target  = (const float*)d_in[1];
    const float* enc_Wih = (const float*)d_in[2];
    const float* enc_Whh = (const float*)d_in[3];
    const float* enc_b   = (const float*)d_in[4];
    const float* dec_Wih = (const float*)d_in[5];
    const float* dec_Whh = (const float*)d_in[6];
    const float* dec_b   = (const float*)d_in[7];
    const float* fc_W    = (const float*)d_in[8];
    const float* fc_b    = (const float*)d_in[9];
    const void*  tfmask  = d_in[10];

    uint8_t* p = (uint8_t*)d_ws;
    auto carve = [&](size_t bytes) { void* rv = (void*)p; p += (bytes + 255) & ~(size_t)255; return rv; };
    f16* hA   = (f16*)carve((size_t)B_ * H_ * 2);
    f16* hB   = (f16*)carve((size_t)B_ * H_ * 2);
    f16* nxt  = (f16*)carve((size_t)B_ * I_ * 2);
    int* flag = (int*)carve(256);
    int* bars = (int*)carve(8192);    // bars[0]=root, bars[32 + lf*32]=leaf lf

    detect_mask<<<1, 128, 0, stream>>>((const unsigned int*)tfmask, flag);
    hipMemsetAsync(hA, 0, (size_t)B_ * H_ * 2, stream);      // h0 = 0 (replay-safe)
    hipMemsetAsync(bars, 0, 8192, stream);                   // counters = 0 per replay

    seq2seq<<<256, 256, 0, stream>>>(
        x, target, enc_Wih, enc_Whh, enc_b, dec_Wih, dec_Whh, dec_b, fc_W, fc_b,
        (const unsigned char*)tfmask, flag, hA, hB, nxt, (float*)d_out,
        bars, bars + 32);
}

// Round 3
// 24033.662 us; speedup vs baseline: 1.6781x; 1.3670x over previous
//
#include <hip/hip_runtime.h>
#include <stdint.h>

#define B_ 64
#define S_ 512
#define I_ 1024
#define H_ 1024

typedef _Float16 f16;
typedef _Float16 f16x8 __attribute__((ext_vector_type(8)));
typedef float f32x4 __attribute__((ext_vector_type(4)));

__device__ __forceinline__ f32x4 mfma16(f16x8 a, f16x8 b, f32x4 c) {
    return __builtin_amdgcn_mfma_f32_16x16x32_f16(a, b, c, 0, 0, 0);
}
__device__ __forceinline__ float sigm(float x)  { return 1.f / (1.f + __expf(-x)); }
__device__ __forceinline__ float tanh_(float x) { return 1.f - 2.f / (1.f + __expf(2.f * x)); }

__device__ __forceinline__ f16x8 cvt8(const float* p) {
    float4 u = *reinterpret_cast<const float4*>(p);
    float4 v = *reinterpret_cast<const float4*>(p + 4);
    return f16x8{(f16)u.x,(f16)u.y,(f16)u.z,(f16)u.w,
                 (f16)v.x,(f16)v.y,(f16)v.z,(f16)v.w};
}

// LLC-coherent access: loads bypass L1/L2 (no stale lines), stores write through
// to LLC. Grid barrier therefore needs NO cache maintenance (no wbl2/inv).
__device__ __forceinline__ f16x8 ld16cg(const f16* p) {
    union { unsigned long long u[2]; f16x8 v; } t;
    t.u[0] = __hip_atomic_load((const unsigned long long*)p,
                               __ATOMIC_RELAXED, __HIP_MEMORY_SCOPE_AGENT);
    t.u[1] = __hip_atomic_load((const unsigned long long*)(p + 4),
                               __ATOMIC_RELAXED, __HIP_MEMORY_SCOPE_AGENT);
    return t.v;
}
__device__ __forceinline__ void st8cg(f16* p, float a, float b, float c, float d) {
    union { f16 h[4]; unsigned long long u; } t;
    t.h[0] = (f16)a; t.h[1] = (f16)b; t.h[2] = (f16)c; t.h[3] = (f16)d;
    __hip_atomic_store((unsigned long long*)p, t.u,
                       __ATOMIC_RELAXED, __HIP_MEMORY_SCOPE_AGENT);
}

// ---------------------------------------------------------------------------
__global__ void detect_mask(const unsigned int* __restrict__ m, int* __restrict__ flag) {
    __shared__ int ok;
    if (threadIdx.x == 0) ok = 1;
    __syncthreads();
    unsigned w = m[threadIdx.x];
    bool is4 = (w == 0u) || (w == 1u) || (w == 0x3F800000u);
    if (!is4) atomicAnd(&ok, 0);
    __syncthreads();
    if (threadIdx.x == 0) *flag = ok;
}

// ---------------------------------------------------------------------------
// Fence-free two-level monotonic grid barrier, split into arrive/wait so
// off-critical-path work (pred GEMM) can overlap other blocks' arrivals.
// ---------------------------------------------------------------------------
__device__ __forceinline__ void gbar_arrive(int* root, int* leaf, int bar, int blk) {
    asm volatile("s_waitcnt vmcnt(0)" ::: "memory");   // my sc1 stores at LLC
    __syncthreads();
    if (threadIdx.x == 0) {
        const int lf  = blk & 31;
        const int old = __hip_atomic_fetch_add(leaf + lf * 32, 1,
                            __ATOMIC_RELAXED, __HIP_MEMORY_SCOPE_AGENT);
        if (old == bar * 8 - 1)
            __hip_atomic_fetch_add(root, 1, __ATOMIC_RELAXED, __HIP_MEMORY_SCOPE_AGENT);
    }
}
__device__ __forceinline__ void gbar_wait(int* root, int bar) {
    if (threadIdx.x == 0) {
        const int tgt = bar * 32;
        while (__hip_atomic_load(root, __ATOMIC_RELAXED, __HIP_MEMORY_SCOPE_AGENT) < tgt)
            __builtin_amdgcn_s_sleep(1);
    }
    __syncthreads();
}

// ---------------------------------------------------------------------------
// Persistent whole-sequence kernel. 256 blocks x 256 threads, 1 block/CU
// (LDS 148.5 KB). Weights live in LDS (frees ~128 VGPRs for deep load
// pipelining). Decoder uses the fused matrix Wsum = Whh + Wih@fcW so each
// step needs ONE h broadcast + ONE barrier; pred is computed off the
// critical path between arrive and wait.
// ---------------------------------------------------------------------------
__global__ __launch_bounds__(256, 1) void seq2seq(
    const float* __restrict__ x, const float* __restrict__ target,
    const float* __restrict__ eWih, const float* __restrict__ eWhh, const float* __restrict__ eb,
    const float* __restrict__ dWih, const float* __restrict__ dWhh, const float* __restrict__ db,
    const float* __restrict__ fcW, const float* __restrict__ fcbv,
    const unsigned char* __restrict__ mask, const int* __restrict__ flag,
    f16* hA, f16* hB, float* __restrict__ out,
    int* root, int* leaf)
{
    const int blk = blockIdx.x, tid = threadIdx.x;
    const int w = tid >> 6, lane = tid & 63;
    const int r = lane & 15, q = lane >> 4;

    // LDS: [sel][slot][lane*8 f16]. sel0: enc Wih(slots 0-31)+Whh(32-63);
    // after encoder slots 0-31 are overwritten with Wsum. sel1: dec Wih+Whh.
    __shared__ __align__(16) f16 wlds[2][64][512];     // 128 KiB
    __shared__ float part[4][64][17];                  // 17.4 KiB
    __shared__ __align__(16) float c0s[16];

    // ---- one-time weight fill: global f32 -> LDS f16 frags (own-lane only) ----
    {
        const long Wrow = (long)(r >> 2) * H_ + 4 * blk + (r & 3);
        #pragma unroll
        for (int i = 0; i < 16; ++i) {
            const int kk = 4 * i + w;
            const long off = (kk < 32) ? (Wrow * I_ + kk * 32 + q * 8)
                                       : (Wrow * H_ + (kk - 32) * 32 + q * 8);
            *reinterpret_cast<f16x8*>(&wlds[0][kk][lane * 8]) =
                cvt8(((kk < 32) ? eWih : eWhh) + off);
            *reinterpret_cast<f16x8*>(&wlds[1][kk][lane * 8]) =
                cvt8(((kk < 32) ? dWih : dWhh) + off);
        }
    }
    // pred weights in registers (blk<64 owns fc cols [16*blk,16*blk+16))
    f16x8 wF[8];
    f32x4 fcb4 = {0.f,0.f,0.f,0.f};
    if (blk < 64) {
        #pragma unroll
        for (int i = 0; i < 8; ++i) {
            const int kk = 4 * i + w;
            wF[i] = cvt8(fcW + (long)(16 * blk + r) * H_ + kk * 32 + q * 8);
        }
        fcb4 = *reinterpret_cast<const f32x4*>(fcbv + 16 * blk + (tid & 3) * 4);
    }
    f32x4 bE[4], bD[4];
    #pragma unroll
    for (int g = 0; g < 4; ++g) {
        bE[g] = *reinterpret_cast<const f32x4*>(eb + g * H_ + 4 * blk);
        bD[g] = *reinterpret_cast<const f32x4*>(db + g * H_ + 4 * blk);
    }
    const int f4 = *flag;

    float c[4] = {0.f, 0.f, 0.f, 0.f};
    int bar = 0;
    f16 *hin = hA, *hout = hB;

    // one LSTM cell step with f32 global input rows (x or x[:,S-1,:])
    auto cell_f32in = [&](const float* xs, int sel, const f32x4 (&bias)[4]) {
        const f32x4 z = {0.f,0.f,0.f,0.f};
        f32x4 acc[4] = {z,z,z,z};
        #pragma unroll
        for (int i = 0; i < 8; ++i) {                  // input half of K
            const int kk = 4 * i + w;
            const f16x8 bw = *reinterpret_cast<const f16x8*>(&wlds[sel][kk][lane * 8]);
            #pragma unroll
            for (int m4 = 0; m4 < 4; ++m4) {
                const f16x8 a = cvt8(xs + (long)(16 * m4 + r) * (S_ * I_) + kk * 32 + q * 8);
                acc[m4] = mfma16(a, bw, acc[m4]);
            }
        }
        #pragma unroll
        for (int i = 0; i < 8; ++i) {                  // h half of K (LLC loads)
            const int kk = 4 * i + w;
            const f16x8 bw = *reinterpret_cast<const f16x8*>(&wlds[sel][32 + kk][lane * 8]);
            #pragma unroll
            for (int m4 = 0; m4 < 4; ++m4) {
                const f16x8 a = ld16cg(hin + (long)(16 * m4 + r) * H_ + kk * 32 + q * 8);
                acc[m4] = mfma16(a, bw, acc[m4]);
            }
        }
        #pragma unroll
        for (int m4 = 0; m4 < 4; ++m4)
            #pragma unroll
            for (int t2 = 0; t2 < 4; ++t2)
                part[w][16 * m4 + q * 4 + t2][r] = acc[m4][t2];
        __syncthreads();
        if (tid < 64) {
            const int row = tid;
            float hv[4];
            #pragma unroll
            for (int jj = 0; jj < 4; ++jj) {
                float gv[4];
                #pragma unroll
                for (int g = 0; g < 4; ++g)
                    gv[g] = part[0][row][g*4+jj] + part[1][row][g*4+jj]
                          + part[2][row][g*4+jj] + part[3][row][g*4+jj] + bias[g][jj];
                const float iv = sigm(gv[0]), fv = sigm(gv[1]);
                const float gg = tanh_(gv[2]), ov = sigm(gv[3]);
                c[jj] = fv * c[jj] + iv * gg;
                hv[jj] = ov * tanh_(c[jj]);
            }
            st8cg(hout + (long)row * H_ + 4 * blk, hv[0], hv[1], hv[2], hv[3]);
        }
    };

    // ---- encoder: 512 steps, 1 barrier each ----
    for (int s = 0; s < S_; ++s) {
        cell_f32in(x + (long)s * I_, 0, bE);
        ++bar; gbar_arrive(root, leaf, bar, blk); gbar_wait(root, bar);
        f16* t_ = hin; hin = hout; hout = t_;
    }

    // ---- one-time fused-matrix precompute (into freed enc-Wih LDS slots) ----
    // Wsum[g,k] = Whh_d[g,k] + sum_j Wih_d[g,j]*fcW[j,k]  (f32 accumulation)
    {
        const long Wrow = (long)(r >> 2) * H_ + 4 * blk + (r & 3);
        const float* wr = dWih + Wrow * I_;
        for (int i = 0; i < 8; ++i) {
            const int kk = 4 * i + w;
            const int k0 = kk * 32 + q * 8;
            float s0=0,s1=0,s2=0,s3=0,s4=0,s5=0,s6=0,s7=0;
            for (int j = 0; j < I_; ++j) {
                const float wv = wr[j];
                const float4 a  = *reinterpret_cast<const float4*>(&fcW[(long)j * H_ + k0]);
                const float4 b2 = *reinterpret_cast<const float4*>(&fcW[(long)j * H_ + k0 + 4]);
                s0 += wv*a.x;  s1 += wv*a.y;  s2 += wv*a.z;  s3 += wv*a.w;
                s4 += wv*b2.x; s5 += wv*b2.y; s6 += wv*b2.z; s7 += wv*b2.w;
            }
            const f16x8 whh = *reinterpret_cast<const f16x8*>(&wlds[1][32 + kk][lane * 8]);
            f16x8 o;
            o[0]=(f16)((float)whh[0]+s0); o[1]=(f16)((float)whh[1]+s1);
            o[2]=(f16)((float)whh[2]+s2); o[3]=(f16)((float)whh[3]+s3);
            o[4]=(f16)((float)whh[4]+s4); o[5]=(f16)((float)whh[5]+s5);
            o[6]=(f16)((float)whh[6]+s6); o[7]=(f16)((float)whh[7]+s7);
            *reinterpret_cast<f16x8*>(&wlds[0][kk][lane * 8]) = o;
        }
        if (tid < 16) {                                // c0_g = sum_j Wih_d[g,j]*fc_b[j]
            const int g = tid >> 2, jj = tid & 3;
            const float* wr2 = dWih + ((long)g * H_ + 4 * blk + jj) * I_;
            float s = 0.f;
            for (int j = 0; j < I_; ++j) s += wr2[j] * fcbv[j];
            c0s[g * 4 + jj] = s;
        }
        __syncthreads();
    }
    f32x4 bDc[4];
    #pragma unroll
    for (int g = 0; g < 4; ++g)
        bDc[g] = bD[g] + *reinterpret_cast<const f32x4*>(&c0s[g * 4]);

    // ---- decoder step 0: input = x[:,S-1,:] ----
    cell_f32in(x + (long)(S_ - 1) * I_, 1, bD);
    ++bar; gbar_arrive(root, leaf, bar, blk); gbar_wait(root, bar);
    { f16* t_ = hin; hin = hout; hout = t_; }

    // ---- decoder steps 1..511: one barrier each; pred_{t-1} inside the
    // ---- arrive->wait window (off the critical path) ----
    for (int t = 1; t < S_; ++t) {
        const bool mk = f4 ? (reinterpret_cast<const int*>(mask)[t - 1] != 0)
                           : (mask[t - 1] != 0);
        f16x8 ha[8][4];
        #pragma unroll
        for (int i = 0; i < 8; ++i) {
            const int kk = 4 * i + w;
            #pragma unroll
            for (int m4 = 0; m4 < 4; ++m4)
                ha[i][m4] = ld16cg(hin + (long)(16 * m4 + r) * H_ + kk * 32 + q * 8);
        }
        const f32x4 z = {0.f,0.f,0.f,0.f};
        f32x4 acc[4] = {z,z,z,z};
        if (mk) {                                      // gates = Wih*target + Whh*h
            const float* ts = target + (long)(t - 1) * I_;
            #pragma unroll
            for (int i = 0; i < 8; ++i) {
                const int kk = 4 * i + w;
                const f16x8 bw = *reinterpret_cast<const f16x8*>(&wlds[1][kk][lane * 8]);
                const f16x8 bh = *reinterpret_cast<const f16x8*>(&wlds[1][32 + kk][lane * 8]);
                #pragma unroll
                for (int m4 = 0; m4 < 4; ++m4) {
                    const f16x8 a = cvt8(ts + (long)(16 * m4 + r) * (S_ * I_) + kk * 32 + q * 8);
                    acc[m4] = mfma16(a, bw, acc[m4]);
                    acc[m4] = mfma16(ha[i][m4], bh, acc[m4]);
                }
            }
        } else {                                       // gates = Wsum*h (+c0 in bias)
            #pragma unroll
            for (int i = 0; i < 8; ++i) {
                const int kk = 4 * i + w;
                const f16x8 bs = *reinterpret_cast<const f16x8*>(&wlds[0][kk][lane * 8]);
                #pragma unroll
                for (int m4 = 0; m4 < 4; ++m4)
                    acc[m4] = mfma16(ha[i][m4], bs, acc[m4]);
            }
        }
        #pragma unroll
        for (int m4 = 0; m4 < 4; ++m4)
            #pragma unroll
            for (int t2 = 0; t2 < 4; ++t2)
                part[w][16 * m4 + q * 4 + t2][r] = acc[m4][t2];
        __syncthreads();
        if (tid < 64) {
            const int row = tid;
            float hv[4];
            #pragma unroll
            for (int jj = 0; jj < 4; ++jj) {
                float gv[4];
                #pragma unroll
                for (int g = 0; g < 4; ++g)
                    gv[g] = part[0][row][g*4+jj] + part[1][row][g*4+jj]
                          + part[2][row][g*4+jj] + part[3][row][g*4+jj]
                          + (mk ? bD[g][jj] : bDc[g][jj]);
                const float iv = sigm(gv[0]), fv = sigm(gv[1]);
                const float gg = tanh_(gv[2]), ov = sigm(gv[3]);
                c[jj] = fv * c[jj] + iv * gg;
                hv[jj] = ov * tanh_(c[jj]);
            }
            st8cg(hout + (long)row * H_ + 4 * blk, hv[0], hv[1], hv[2], hv[3]);
        }
        ++bar; gbar_arrive(root, leaf, bar, blk);
        if (blk < 64) {                                // pred_{t-1} = h_{t-1} @ fcW^T
            f32x4 pa[4] = {z,z,z,z};
            #pragma unroll
            for (int i = 0; i < 8; ++i)
                #pragma unroll
                for (int m4 = 0; m4 < 4; ++m4)
                    pa[m4] = mfma16(ha[i][m4], wF[i], pa[m4]);
            #pragma unroll
            for (int m4 = 0; m4 < 4; ++m4)
                #pragma unroll
                for (int t2 = 0; t2 < 4; ++t2)
                    part[w][16 * m4 + q * 4 + t2][r] = pa[m4][t2];
            __syncthreads();
            const int prow = tid >> 2, pcg = (tid & 3) * 4;
            f32x4 pv;
            #pragma unroll
            for (int e = 0; e < 4; ++e)
                pv[e] = part[0][prow][pcg+e] + part[1][prow][pcg+e]
                      + part[2][prow][pcg+e] + part[3][prow][pcg+e] + fcb4[e];
            *reinterpret_cast<f32x4*>(out + (long)prow * (S_ * I_)
                                      + (long)(t - 1) * I_ + 16 * blk + pcg) = pv;
        }
        gbar_wait(root, bar);
        f16* t_ = hin; hin = hout; hout = t_;
    }

    // ---- epilogue: pred_511 from h_511 (in hin after final swap) ----
    if (blk < 64) {
        const f32x4 z = {0.f,0.f,0.f,0.f};
        f32x4 pa[4] = {z,z,z,z};
        #pragma unroll
        for (int i = 0; i < 8; ++i) {
            const int kk = 4 * i + w;
            #pragma unroll
            for (int m4 = 0; m4 < 4; ++m4)
                pa[m4] = mfma16(ld16cg(hin + (long)(16 * m4 + r) * H_ + kk * 32 + q * 8),
                                wF[i], pa[m4]);
        }
        #pragma unroll
        for (int m4 = 0; m4 < 4; ++m4)
            #pragma unroll
            for (int t2 = 0; t2 < 4; ++t2)
                part[w][16 * m4 + q * 4 + t2][r] = pa[m4][t2];
        __syncthreads();
        const int prow = tid >> 2, pcg = (tid & 3) * 4;
        f32x4 pv;
        #pragma unroll
        for (int e = 0; e < 4; ++e)
            pv[e] = part[0][prow][pcg+e] + part[1][prow][pcg+e]
                  + part[2][prow][pcg+e] + part[3][prow][pcg+e] + fcb4[e];
        *reinterpret_cast<f32x4*>(out + (long)prow * (S_ * I_)
                                  + (long)(S_ - 1) * I_ + 16 * blk + pcg) = pv;
    }
}

// ---------------------------------------------------------------------------
extern "C" void kernel_launch(void* const* d_in, const int* in_sizes, int n_in,
                              void* d_out, int out_size, void* d_ws, size_t ws_size,
                              hipStream_t stream) {
    (void)in_sizes; (void)n_in; (void)out_size; (void)ws_size;
    const float* x       = (const float*)d_in[0];
    const float* target  = (const float*)d_in[1];
    const float* enc_Wih = (const float*)d_in[2];
    const float* enc_Whh = (const float*)d_in[3];
    const float* enc_b   = (const float*)d_in[4];
    const float* dec_Wih = (const float*)d_in[5];
    const float* dec_Whh = (const float*)d_in[6];
    const float* dec_b   = (const float*)d_in[7];
    const float* fc_W    = (const float*)d_in[8];
    const float* fc_b    = (const float*)d_in[9];
    const void*  tfmask  = d_in[10];

    uint8_t* p = (uint8_t*)d_ws;
    auto carve = [&](size_t bytes) { void* rv = (void*)p; p += (bytes + 255) & ~(size_t)255; return rv; };
    f16* hA   = (f16*)carve((size_t)B_ * H_ * 2);
    f16* hB   = (f16*)carve((size_t)B_ * H_ * 2);
    int* flag = (int*)carve(256);
    int* bars = (int*)carve(8192);    // bars[0]=root, bars[32 + lf*32]=leaf lf

    detect_mask<<<1, 128, 0, stream>>>((const unsigned int*)tfmask, flag);
    hipMemsetAsync(hA, 0, (size_t)B_ * H_ * 2, stream);      // h0 = 0 (replay-safe)
    hipMemsetAsync(bars, 0, 8192, stream);                   // counters = 0 per replay

    seq2seq<<<256, 256, 0, stream>>>(
        x, target, enc_Wih, enc_Whh, enc_b, dec_Wih, dec_Whh, dec_b, fc_W, fc_b,
        (const unsigned char*)tfmask, flag, hA, hB, (float*)d_out,
        bars, bars + 32);
}